// Round 1
// baseline (2054.027 us; speedup 1.0000x reference)
//
#include <hip/hip_runtime.h>
#include <math.h>

#define TOKENS   8192
#define HIDDEN   7168
#define NEXPERT  256
#define NGROUP   8
#define GSIZE    32      // NEXPERT / NGROUP
#define TOPKG    4
#define TOPK     8
#define SCALE    2.5f

#define BM 64
#define BN 64
#define BK 32
// thread tile 4x4, 16x16 thread grid = 256 threads

__device__ __forceinline__ float sigmoidf_(float x) {
    return 1.0f / (1.0f + expf(-x));
}

// ---------------------------------------------------------------------------
// Gate GEMM: S[t][e] = sigmoid( sum_k X[t][k] * W[e][k] )
// X: [TOKENS][HIDDEN] row-major, W: [NEXPERT][HIDDEN] row-major (NT gemm).
// ---------------------------------------------------------------------------
__global__ __launch_bounds__(256) void gate_gemm_kernel(
    const float* __restrict__ X, const float* __restrict__ W,
    float* __restrict__ S)
{
    __shared__ float As[BK][BM];   // A transposed: As[k][m]
    __shared__ float Bs[BK][BN];   // B transposed: Bs[k][n]

    const int tid = threadIdx.x;
    const int tx  = tid & 15;      // expert dir (16 threads * TN=4 -> 64)
    const int ty  = tid >> 4;      // token dir  (16 threads * TM=4 -> 64)
    const int bn  = blockIdx.x * BN;   // expert tile base (fastest -> A reuse)
    const int bm  = blockIdx.y * BM;   // token tile base

    // loader mapping: tile is 64 rows x 32 cols = 512 float4; 2 per thread
    const int lrow = tid >> 3;     // 0..31
    const int lc4  = tid & 7;      // 0..7 (float4 column within BK)

    const float* Ap0 = X + (size_t)(bm + lrow)      * HIDDEN + lc4 * 4;
    const float* Ap1 = X + (size_t)(bm + lrow + 32) * HIDDEN + lc4 * 4;
    const float* Bp0 = W + (size_t)(bn + lrow)      * HIDDEN + lc4 * 4;
    const float* Bp1 = W + (size_t)(bn + lrow + 32) * HIDDEN + lc4 * 4;

    float acc[4][4];
#pragma unroll
    for (int i = 0; i < 4; i++)
#pragma unroll
        for (int j = 0; j < 4; j++) acc[i][j] = 0.0f;

    for (int kt = 0; kt < HIDDEN; kt += BK) {
        // global loads first: overlap latency with previous chunk's compute
        const float4 a0 = *(const float4*)(Ap0 + kt);
        const float4 a1 = *(const float4*)(Ap1 + kt);
        const float4 b0 = *(const float4*)(Bp0 + kt);
        const float4 b1 = *(const float4*)(Bp1 + kt);

        __syncthreads();   // previous chunk's compute done before overwrite

        const int kc = lc4 * 4;
        As[kc + 0][lrow] = a0.x; As[kc + 1][lrow] = a0.y;
        As[kc + 2][lrow] = a0.z; As[kc + 3][lrow] = a0.w;
        As[kc + 0][lrow + 32] = a1.x; As[kc + 1][lrow + 32] = a1.y;
        As[kc + 2][lrow + 32] = a1.z; As[kc + 3][lrow + 32] = a1.w;
        Bs[kc + 0][lrow] = b0.x; Bs[kc + 1][lrow] = b0.y;
        Bs[kc + 2][lrow] = b0.z; Bs[kc + 3][lrow] = b0.w;
        Bs[kc + 0][lrow + 32] = b1.x; Bs[kc + 1][lrow + 32] = b1.y;
        Bs[kc + 2][lrow + 32] = b1.z; Bs[kc + 3][lrow + 32] = b1.w;

        __syncthreads();

#pragma unroll
        for (int k = 0; k < BK; k++) {
            const float4 av = *(const float4*)&As[k][ty * 4];
            const float4 bv = *(const float4*)&Bs[k][tx * 4];
            const float a[4] = { av.x, av.y, av.z, av.w };
            const float b[4] = { bv.x, bv.y, bv.z, bv.w };
#pragma unroll
            for (int i = 0; i < 4; i++)
#pragma unroll
                for (int j = 0; j < 4; j++)
                    acc[i][j] = fmaf(a[i], b[j], acc[i][j]);
        }
    }

    // epilogue: fused sigmoid, coalesced float4 stores
#pragma unroll
    for (int i = 0; i < 4; i++) {
        const int row = bm + ty * 4 + i;
        float4 o;
        o.x = sigmoidf_(acc[i][0]);
        o.y = sigmoidf_(acc[i][1]);
        o.z = sigmoidf_(acc[i][2]);
        o.w = sigmoidf_(acc[i][3]);
        *(float4*)&S[(size_t)row * NEXPERT + bn + tx * 4] = o;
    }
}

// ---------------------------------------------------------------------------
// Routing: in-place on S (scores -> final gate weights). One block per token.
// Replicates jax semantics exactly:
//   swb = score + bias; group score = sum(top2(swb within group));
//   keep top-4 groups; top-8 experts by (kept ? swb : 0.0);
//   out = selected ? score * 2.5 / (sum selected scores + 1e-20) : 0
// Strict '>' scans keep the earliest index == jax.lax.top_k tie-break.
// ---------------------------------------------------------------------------
__global__ __launch_bounds__(256) void route_kernel(
    float* __restrict__ S, const float* __restrict__ bias)
{
    __shared__ float s_sc[NEXPERT];
    __shared__ float s_swb[NEXPERT];
    __shared__ float s_gsc[NGROUP];
    __shared__ int   s_gsel[NGROUP];
    __shared__ unsigned char s_sel[NEXPERT];
    __shared__ float s_rcp;

    const int t = blockIdx.x;
    const int e = threadIdx.x;

    const float sc = S[(size_t)t * NEXPERT + e];
    s_sc[e]  = sc;
    s_swb[e] = sc + bias[e];
    s_sel[e] = 0;
    __syncthreads();

    if (e < NGROUP) {
        // top-2 sum within group e
        float m1 = -INFINITY, m2 = -INFINITY;
        for (int i = 0; i < GSIZE; i++) {
            const float v = s_swb[e * GSIZE + i];
            if (v > m1)      { m2 = m1; m1 = v; }
            else if (v > m2) { m2 = v; }
        }
        s_gsc[e]  = m1 + m2;
        s_gsel[e] = 0;
    }
    __syncthreads();

    if (e == 0) {
        // top-4 groups
        for (int r = 0; r < TOPKG; r++) {
            int best = 0; float bv = -INFINITY;
            for (int g = 0; g < NGROUP; g++) {
                if (!s_gsel[g] && s_gsc[g] > bv) { bv = s_gsc[g]; best = g; }
            }
            s_gsel[best] = 1;
        }
        // top-8 experts over masked swb (masked -> 0.0f, mirroring swb*mask)
        float sum = 0.0f;
        for (int r = 0; r < TOPK; r++) {
            int best = 0; float bv = -INFINITY;
            for (int i = 0; i < NEXPERT; i++) {
                if (s_sel[i]) continue;
                const float v = s_gsel[i >> 5] ? s_swb[i] : 0.0f;
                if (v > bv) { bv = v; best = i; }
            }
            s_sel[best] = 1;
            sum += s_sc[best];
        }
        s_rcp = SCALE / (sum + 1e-20f);
    }
    __syncthreads();

    S[(size_t)t * NEXPERT + e] = s_sel[e] ? sc * s_rcp : 0.0f;
}

extern "C" void kernel_launch(void* const* d_in, const int* in_sizes, int n_in,
                              void* d_out, int out_size, void* d_ws, size_t ws_size,
                              hipStream_t stream) {
    const float* X    = (const float*)d_in[0];   // [8192, 7168]
    const float* W    = (const float*)d_in[1];   // [256, 7168]
    const float* bias = (const float*)d_in[2];   // [256]
    float* out = (float*)d_out;                  // [8192, 256]

    dim3 ggrid(NEXPERT / BN, TOKENS / BM);       // (4, 128)
    gate_gemm_kernel<<<ggrid, 256, 0, stream>>>(X, W, out);
    route_kernel<<<TOKENS, 256, 0, stream>>>(out, bias);
}

// Round 2
// 701.588 us; speedup vs baseline: 2.9277x; 2.9277x over previous
//
#include <hip/hip_runtime.h>
#include <math.h>

#define TOKENS   8192
#define HIDDEN   7168
#define NEXPERT  256
#define NGROUP   8
#define GSIZE    32      // NEXPERT / NGROUP
#define TOPKG    4
#define TOPK     8
#define SCALE    2.5f

#define BM 64
#define BN 64
#define BK 64
// thread tile 4x4, 16x16 thread grid = 256 threads

__device__ __forceinline__ float sigmoidf_(float x) {
    return 1.0f / (1.0f + expf(-x));
}

// ---------------------------------------------------------------------------
// Gate GEMM: S[t][e] = sigmoid( sum_k X[t][k] * W[e][k] )
// X: [TOKENS][HIDDEN] row-major, W: [NEXPERT][HIDDEN] row-major (NT gemm).
// LDS staged transposed (As[k][m]); loader mapped so consecutive lanes hit
// consecutive LDS addresses (+4 pad -> <=2-way bank aliasing, free per m136).
// Next chunk's global loads issued before the FMA loop (SW pipeline).
// ---------------------------------------------------------------------------
__global__ __launch_bounds__(256) void gate_gemm_kernel(
    const float* __restrict__ X, const float* __restrict__ W,
    float* __restrict__ S)
{
    __shared__ float As[BK][BM + 4];
    __shared__ float Bs[BK][BN + 4];

    const int tid = threadIdx.x;
    const int tx  = tid & 15;      // expert dir (16 threads * 4 = 64)
    const int ty  = tid >> 4;      // token dir  (16 threads * 4 = 64)
    const int bn  = blockIdx.x * BN;   // expert tile (fastest -> A reuse in LLC)
    const int bm  = blockIdx.y * BM;   // token tile

    // loader: lane -> (row lr+16p, f4col lc). Consecutive lanes ->
    // consecutive rows -> consecutive LDS write addresses (conflict-free).
    const int lr = tid & 15;       // row base 0..15
    const int lc = tid >> 4;       // f4 column 0..15 (k-offset lc*4)
    const float* Ap = X + (size_t)(bm + lr) * HIDDEN + lc * 4;
    const float* Bp = W + (size_t)(bn + lr) * HIDDEN + lc * 4;

    float acc[4][4];
#pragma unroll
    for (int i = 0; i < 4; i++)
#pragma unroll
        for (int j = 0; j < 4; j++) acc[i][j] = 0.0f;

    float4 a[4], b[4];
#pragma unroll
    for (int p = 0; p < 4; p++) {
        a[p] = *(const float4*)(Ap + (size_t)(p * 16) * HIDDEN);
        b[p] = *(const float4*)(Bp + (size_t)(p * 16) * HIDDEN);
    }

    for (int kt = 0; kt < HIDDEN; kt += BK) {
        __syncthreads();   // previous chunk's compute done before overwrite

        const int kc = lc * 4;
#pragma unroll
        for (int p = 0; p < 4; p++) {
            const int r = lr + p * 16;
            As[kc + 0][r] = a[p].x; As[kc + 1][r] = a[p].y;
            As[kc + 2][r] = a[p].z; As[kc + 3][r] = a[p].w;
            Bs[kc + 0][r] = b[p].x; Bs[kc + 1][r] = b[p].y;
            Bs[kc + 2][r] = b[p].z; Bs[kc + 3][r] = b[p].w;
        }

        __syncthreads();

        // issue next chunk's global loads; FMA loop below hides their latency
        if (kt + BK < HIDDEN) {
#pragma unroll
            for (int p = 0; p < 4; p++) {
                a[p] = *(const float4*)(Ap + kt + BK + (size_t)(p * 16) * HIDDEN);
                b[p] = *(const float4*)(Bp + kt + BK + (size_t)(p * 16) * HIDDEN);
            }
        }

#pragma unroll
        for (int k = 0; k < BK; k++) {
            const float4 av = *(const float4*)&As[k][ty * 4];
            const float4 bv = *(const float4*)&Bs[k][tx * 4];
            const float aa[4] = { av.x, av.y, av.z, av.w };
            const float bb[4] = { bv.x, bv.y, bv.z, bv.w };
#pragma unroll
            for (int i = 0; i < 4; i++)
#pragma unroll
                for (int j = 0; j < 4; j++)
                    acc[i][j] = fmaf(aa[i], bb[j], acc[i][j]);
        }
    }

    // epilogue: fused sigmoid, coalesced float4 stores
#pragma unroll
    for (int i = 0; i < 4; i++) {
        const int row = bm + ty * 4 + i;
        float4 o;
        o.x = sigmoidf_(acc[i][0]);
        o.y = sigmoidf_(acc[i][1]);
        o.z = sigmoidf_(acc[i][2]);
        o.w = sigmoidf_(acc[i][3]);
        *(float4*)&S[(size_t)row * NEXPERT + bn + tx * 4] = o;
    }
}

// ---------------------------------------------------------------------------
// Routing: one WAVE per token, 4 tokens per 256-thread block. All state in
// registers; cross-lane via shuffles. Replicates jax semantics exactly:
//   swb = score + bias; group score = sum(top2(swb within group));
//   keep top-4 groups (tie -> lowest group index);
//   top-8 experts by (kept ? swb : 0.0), tie -> lowest expert index;
//   out = selected ? score * 2.5 / (sum selected scores + 1e-20) : 0
// Lane l holds experts 4l..4l+3; group g = lanes 8g..8g+7 (aligned).
// ---------------------------------------------------------------------------
__global__ __launch_bounds__(256) void route_kernel(
    float* __restrict__ S, const float* __restrict__ bias)
{
    const int lane = threadIdx.x & 63;
    const int wave = threadIdx.x >> 6;
    const int t    = blockIdx.x * 4 + wave;

    const float4 sc4 = *(const float4*)&S[(size_t)t * NEXPERT + lane * 4];
    const float4 b4  = *(const float4*)&bias[lane * 4];
    float sc[4]  = { sc4.x, sc4.y, sc4.z, sc4.w };
    float swb[4] = { sc4.x + b4.x, sc4.y + b4.y, sc4.z + b4.z, sc4.w + b4.w };

    // ---- per-lane top-2 of 4 ----
    float m1 = -INFINITY, m2 = -INFINITY;
#pragma unroll
    for (int j = 0; j < 4; j++) {
        const float v = swb[j];
        if (v > m1)      { m2 = m1; m1 = v; }
        else if (v > m2) { m2 = v; }
    }
    // ---- merge top-2 across the 8 lanes of my group (xor 1,2,4) ----
#pragma unroll
    for (int s = 1; s < 8; s <<= 1) {
        const float o1 = __shfl_xor(m1, s, 64);
        const float o2 = __shfl_xor(m2, s, 64);
        const float hi = fmaxf(m1, o1);
        const float lo = fminf(m1, o1);
        m2 = fmaxf(lo, fmaxf(m2, o2));
        m1 = hi;
    }
    const float gs = m1 + m2;          // my group's score (same in all 8 lanes)

    // ---- top-4 groups: rank my group among all 8 (tie -> lower index) ----
    float gsc[NGROUP];
#pragma unroll
    for (int g = 0; g < NGROUP; g++) gsc[g] = __shfl(gs, g * 8, 64);
    const int myg = lane >> 3;
    int rank = 0;
#pragma unroll
    for (int g = 0; g < NGROUP; g++)
        rank += (gsc[g] > gs) || (gsc[g] == gs && g < myg);
    const bool kept = (rank < TOPKG);

    // ---- masked scores (masked -> literal 0.0, mirroring swb*mask) ----
    float v[4];
#pragma unroll
    for (int j = 0; j < 4; j++) v[j] = kept ? swb[j] : 0.0f;

    // ---- top-8 extraction: 8 rounds of wave argmax (lowest idx on ties) ----
    float sum = 0.0f;
    int selmask = 0;
    for (int r = 0; r < TOPK; r++) {
        float bv = -INFINITY;
        int   bi = 0x7fffffff;
#pragma unroll
        for (int j = 0; j < 4; j++) {
            const bool avail = ((selmask >> j) & 1) == 0;
            if (avail && v[j] > bv) { bv = v[j]; bi = lane * 4 + j; }
        }
#pragma unroll
        for (int s = 1; s < 64; s <<= 1) {
            const float ov = __shfl_xor(bv, s, 64);
            const int   oi = __shfl_xor(bi, s, 64);
            if (ov > bv || (ov == bv && oi < bi)) { bv = ov; bi = oi; }
        }
        const int wl = bi >> 2, wj = bi & 3;   // wave-uniform after butterfly
        const float mysc = (wj == 0) ? sc[0] : (wj == 1) ? sc[1]
                         : (wj == 2) ? sc[2] : sc[3];
        sum += __shfl(mysc, wl, 64);
        if (lane == wl) selmask |= (1 << wj);
    }

    const float rcp = SCALE / (sum + 1e-20f);
    float4 o;
    o.x = (selmask & 1) ? sc[0] * rcp : 0.0f;
    o.y = (selmask & 2) ? sc[1] * rcp : 0.0f;
    o.z = (selmask & 4) ? sc[2] * rcp : 0.0f;
    o.w = (selmask & 8) ? sc[3] * rcp : 0.0f;
    *(float4*)&S[(size_t)t * NEXPERT + lane * 4] = o;
}

extern "C" void kernel_launch(void* const* d_in, const int* in_sizes, int n_in,
                              void* d_out, int out_size, void* d_ws, size_t ws_size,
                              hipStream_t stream) {
    const float* X    = (const float*)d_in[0];   // [8192, 7168]
    const float* W    = (const float*)d_in[1];   // [256, 7168]
    const float* bias = (const float*)d_in[2];   // [256]
    float* out = (float*)d_out;                  // [8192, 256]

    dim3 ggrid(NEXPERT / BN, TOKENS / BM);       // (4, 128)
    gate_gemm_kernel<<<ggrid, 256, 0, stream>>>(X, W, out);
    route_kernel<<<TOKENS / 4, 256, 0, stream>>>(out, bias);
}

// Round 3
// 504.987 us; speedup vs baseline: 4.0675x; 1.3893x over previous
//
#include <hip/hip_runtime.h>
#include <math.h>

#define TOKENS   8192
#define HIDDEN   7168
#define NEXPERT  256
#define NGROUP   8
#define TOPKG    4
#define TOPK     8
#define SCALE    2.5f

// GEMM tiling: 64 tokens x 128 experts per block, K-tile 64, split-K 2.
// grid (2 n, 128 m, 2 k) = 512 blocks -> 2 blocks/CU, 8 waves/CU.
#define BM 64
#define BN 128
#define BK 64
#define KSPLIT 2
#define KPB (HIDDEN / KSPLIT)   // 3584
#define NT  (KPB / BK)          // 56

typedef _Float16 half8 __attribute__((ext_vector_type(8)));
typedef _Float16 half4 __attribute__((ext_vector_type(4)));
typedef float    floatx4 __attribute__((ext_vector_type(4)));

// XOR swizzle in 16B (8-half) groups: row stride 64 halves = 128 B.
// Frag reads and staged writes both land <=2-way bank aliasing (free, m136).
__device__ __forceinline__ int swz(int r, int k) {
    return r * 64 + ((((k >> 3) ^ (r & 7)) << 3) | (k & 7));
}

__device__ __forceinline__ void cvt_store(_Float16* __restrict__ Hh,
                                          _Float16* __restrict__ Hl,
                                          int r, int k0, float4 v) {
    half4 h, l;
    h[0] = (_Float16)v.x; h[1] = (_Float16)v.y;
    h[2] = (_Float16)v.z; h[3] = (_Float16)v.w;
    l[0] = (_Float16)(v.x - (float)h[0]);
    l[1] = (_Float16)(v.y - (float)h[1]);
    l[2] = (_Float16)(v.z - (float)h[2]);
    l[3] = (_Float16)(v.w - (float)h[3]);
    const int a = swz(r, k0);
    *(half4*)&Hh[a] = h;
    *(half4*)&Hl[a] = l;
}

// ---------------------------------------------------------------------------
// zero d_out (poisoned 0xAA each iteration; atomics need 0 init)
// ---------------------------------------------------------------------------
__global__ __launch_bounds__(256) void zero_kernel(float* __restrict__ O) {
    const int i = blockIdx.x * 256 + threadIdx.x;
    *(float4*)&O[(size_t)i * 4] = float4{0.f, 0.f, 0.f, 0.f};
}

// ---------------------------------------------------------------------------
// Gate GEMM via fp16-split 3-product MFMA. OUT accumulates raw fp32 logits.
//   x = xh + xl (fp16 RNE), logit = sum xh*wh + xh*wl + xl*wh  (fp32 acc)
// Dropped xl*wl term <= ~5e-6 coherent -> fp32-equivalent for routing.
// ---------------------------------------------------------------------------
__global__ __launch_bounds__(256, 2) void gate_gemm_kernel(
    const float* __restrict__ X, const float* __restrict__ W,
    float* __restrict__ OUT)
{
    __shared__ _Float16 Ah[BM * BK], Al[BM * BK];   // 8 KB each
    __shared__ _Float16 Bh[BN * BK], Bl[BN * BK];   // 16 KB each -> 48 KB total

    const int tid = threadIdx.x;
    const int nb  = blockIdx.x * BN;
    const int mb  = blockIdx.y * BM;
    const int kb  = blockIdx.z * KPB;

    // staging map: A 64x64 fp32 -> 4 float4/thread; B 128x64 -> 8 float4/thread
    const int am = tid & 63,  ak = (tid >> 6) << 4;   // 16 k per thread
    const int bn = tid & 127, bk = (tid >> 7) << 5;   // 32 k per thread
    const float* Aptr = X + (size_t)(mb + am) * HIDDEN + kb + ak;
    const float* Bptr = W + (size_t)(nb + bn) * HIDDEN + kb + bk;

    float4 av[4], bv[8];
#pragma unroll
    for (int q = 0; q < 4; q++) av[q] = *(const float4*)(Aptr + q * 4);
#pragma unroll
    for (int q = 0; q < 8; q++) bv[q] = *(const float4*)(Bptr + q * 4);

    // wave tiling: 4 waves as 2(m) x 2(n); wave tile 32m x 64n
    const int lane = tid & 63, wave = tid >> 6;
    const int wm = (wave >> 1) * 32, wn = (wave & 1) * 64;
    const int fr = lane & 15, quad = lane >> 4;

    floatx4 acc[2][4];
#pragma unroll
    for (int i = 0; i < 2; i++)
#pragma unroll
        for (int j = 0; j < 4; j++) acc[i][j] = floatx4{0.f, 0.f, 0.f, 0.f};

    for (int t = 0; t < NT; t++) {
        __syncthreads();   // prev tile's frag reads done
#pragma unroll
        for (int q = 0; q < 4; q++) cvt_store(Ah, Al, am, ak + q * 4, av[q]);
#pragma unroll
        for (int q = 0; q < 8; q++) cvt_store(Bh, Bl, bn, bk + q * 4, bv[q]);
        __syncthreads();   // LDS ready

        if (t + 1 < NT) {  // prefetch next tile; MFMA below hides latency
            const int o = (t + 1) * BK;
#pragma unroll
            for (int q = 0; q < 4; q++) av[q] = *(const float4*)(Aptr + o + q * 4);
#pragma unroll
            for (int q = 0; q < 8; q++) bv[q] = *(const float4*)(Bptr + o + q * 4);
        }

#pragma unroll
        for (int ks = 0; ks < 2; ks++) {
            half8 a_h[2], a_l[2], b_h[4], b_l[4];
            const int kk = ks * 32 + quad * 8;
#pragma unroll
            for (int i = 0; i < 2; i++) {
                const int a = swz(wm + i * 16 + fr, kk);
                a_h[i] = *(half8*)&Ah[a];
                a_l[i] = *(half8*)&Al[a];
            }
#pragma unroll
            for (int j = 0; j < 4; j++) {
                const int a = swz(wn + j * 16 + fr, kk);
                b_h[j] = *(half8*)&Bh[a];
                b_l[j] = *(half8*)&Bl[a];
            }
#pragma unroll
            for (int i = 0; i < 2; i++)
#pragma unroll
                for (int j = 0; j < 4; j++) {
                    acc[i][j] = __builtin_amdgcn_mfma_f32_16x16x32_f16(
                        a_l[i], b_h[j], acc[i][j], 0, 0, 0);
                    acc[i][j] = __builtin_amdgcn_mfma_f32_16x16x32_f16(
                        a_h[i], b_l[j], acc[i][j], 0, 0, 0);
                    acc[i][j] = __builtin_amdgcn_mfma_f32_16x16x32_f16(
                        a_h[i], b_h[j], acc[i][j], 0, 0, 0);
                }
        }
    }

    // epilogue: D row = token (A/m, quad*4+reg), col = expert (B/n, lane&15).
    // Two split-K partials: a+b == b+a bitwise -> deterministic.
#pragma unroll
    for (int i = 0; i < 2; i++)
#pragma unroll
        for (int j = 0; j < 4; j++) {
            const int col = nb + wn + j * 16 + fr;
#pragma unroll
            for (int r = 0; r < 4; r++) {
                const int row = mb + wm + i * 16 + quad * 4 + r;
                atomicAdd(&OUT[(size_t)row * NEXPERT + col], acc[i][j][r]);
            }
        }
}

// ---------------------------------------------------------------------------
// Routing: one wave per token; input is raw logits, sigmoid fused here.
// Exact jax semantics incl. lowest-index tie-breaks (see R2 notes).
// ---------------------------------------------------------------------------
__global__ __launch_bounds__(256) void route_kernel(
    float* __restrict__ S, const float* __restrict__ bias)
{
    const int lane = threadIdx.x & 63;
    const int wave = threadIdx.x >> 6;
    const int t    = blockIdx.x * 4 + wave;

    const float4 lg4 = *(const float4*)&S[(size_t)t * NEXPERT + lane * 4];
    const float4 b4  = *(const float4*)&bias[lane * 4];
    float sc[4];
    sc[0] = 1.0f / (1.0f + expf(-lg4.x));
    sc[1] = 1.0f / (1.0f + expf(-lg4.y));
    sc[2] = 1.0f / (1.0f + expf(-lg4.z));
    sc[3] = 1.0f / (1.0f + expf(-lg4.w));
    float swb[4] = { sc[0] + b4.x, sc[1] + b4.y, sc[2] + b4.z, sc[3] + b4.w };

    // per-lane top-2 of 4
    float m1 = -INFINITY, m2 = -INFINITY;
#pragma unroll
    for (int j = 0; j < 4; j++) {
        const float v = swb[j];
        if (v > m1)      { m2 = m1; m1 = v; }
        else if (v > m2) { m2 = v; }
    }
    // merge across the 8 lanes of my group
#pragma unroll
    for (int s = 1; s < 8; s <<= 1) {
        const float o1 = __shfl_xor(m1, s, 64);
        const float o2 = __shfl_xor(m2, s, 64);
        const float hi = fmaxf(m1, o1);
        const float lo = fminf(m1, o1);
        m2 = fmaxf(lo, fmaxf(m2, o2));
        m1 = hi;
    }
    const float gs = m1 + m2;

    // top-4 groups by rank (tie -> lower group index)
    float gsc[NGROUP];
#pragma unroll
    for (int g = 0; g < NGROUP; g++) gsc[g] = __shfl(gs, g * 8, 64);
    const int myg = lane >> 3;
    int rank = 0;
#pragma unroll
    for (int g = 0; g < NGROUP; g++)
        rank += (gsc[g] > gs) || (gsc[g] == gs && g < myg);
    const bool kept = (rank < TOPKG);

    float v[4];
#pragma unroll
    for (int j = 0; j < 4; j++) v[j] = kept ? swb[j] : 0.0f;

    // top-8 experts: 8 rounds of wave argmax (lowest idx on ties)
    float sum = 0.0f;
    int selmask = 0;
    for (int r = 0; r < TOPK; r++) {
        float bv = -INFINITY;
        int   bi = 0x7fffffff;
#pragma unroll
        for (int j = 0; j < 4; j++) {
            const bool avail = ((selmask >> j) & 1) == 0;
            if (avail && v[j] > bv) { bv = v[j]; bi = lane * 4 + j; }
        }
#pragma unroll
        for (int s = 1; s < 64; s <<= 1) {
            const float ov = __shfl_xor(bv, s, 64);
            const int   oi = __shfl_xor(bi, s, 64);
            if (ov > bv || (ov == bv && oi < bi)) { bv = ov; bi = oi; }
        }
        const int wl = bi >> 2, wj = bi & 3;
        const float mysc = (wj == 0) ? sc[0] : (wj == 1) ? sc[1]
                         : (wj == 2) ? sc[2] : sc[3];
        sum += __shfl(mysc, wl, 64);
        if (lane == wl) selmask |= (1 << wj);
    }

    const float rcp = SCALE / (sum + 1e-20f);
    float4 o;
    o.x = (selmask & 1) ? sc[0] * rcp : 0.0f;
    o.y = (selmask & 2) ? sc[1] * rcp : 0.0f;
    o.z = (selmask & 4) ? sc[2] * rcp : 0.0f;
    o.w = (selmask & 8) ? sc[3] * rcp : 0.0f;
    *(float4*)&S[(size_t)t * NEXPERT + lane * 4] = o;
}

extern "C" void kernel_launch(void* const* d_in, const int* in_sizes, int n_in,
                              void* d_out, int out_size, void* d_ws, size_t ws_size,
                              hipStream_t stream) {
    const float* X    = (const float*)d_in[0];   // [8192, 7168]
    const float* W    = (const float*)d_in[1];   // [256, 7168]
    const float* bias = (const float*)d_in[2];   // [256]
    float* out = (float*)d_out;                  // [8192, 256]

    zero_kernel<<<(TOKENS * NEXPERT / 4) / 256, 256, 0, stream>>>(out);
    dim3 ggrid(NEXPERT / BN, TOKENS / BM, KSPLIT);   // (2, 128, 2)
    gate_gemm_kernel<<<ggrid, 256, 0, stream>>>(X, W, out);
    route_kernel<<<TOKENS / 4, 256, 0, stream>>>(out, bias);
}